// Round 16
// baseline (732.869 us; speedup 1.0000x reference)
//
#include <hip/hip_runtime.h>

// GRU: B=256, T=1000, I=64, H=128 (3H=384).
// Round-16: split off x_proj into a parallel pre-pass (all 256 CUs,
// memory-bound, ~70us) stored f16 in d_ws; the sequential scan keeps only
// the h-recurrence: 12 MFMA/wave/step (was 18). Scan body otherwise
// byte-identical to r12 (594us best). r15 lesson: phase time is additive;
// remove work, don't reschedule it. Fallback to r12 kernel if ws_size
// < 196.6MB (runtime-checked, deterministic).

#define Tc 1000
#define Ic 64
#define Hc 128
#define Bc 256
#define G3 (3 * Hc)
#define MBLK 8
#define NBLOCKS 32

typedef _Float16 half8 __attribute__((ext_vector_type(8)));
typedef float f32x4 __attribute__((ext_vector_type(4)));

#define MFMA_F16(A, B, C) __builtin_amdgcn_mfma_f32_16x16x32_f16((A), (B), (C), 0, 0, 0)

__device__ __forceinline__ float fast_sigmoid(float x) {
    return __builtin_amdgcn_rcpf(1.0f + __expf(-x));
}
__device__ __forceinline__ float fast_tanh(float x) {
    return 1.0f - 2.0f * __builtin_amdgcn_rcpf(__expf(2.0f * x) + 1.0f);
}
__device__ __forceinline__ float cvt16(unsigned short u) {
    return (float)__builtin_bit_cast(_Float16, u);
}

// ---------------- pre-pass: x_proj[b][t][g] = x[b][t] . W_ih[g] (raw, f16) ----
__global__ __launch_bounds__(256) void xproj_kernel(
    const float* __restrict__ input,   // [B][T][I]
    const float* __restrict__ W_ih,    // [3H][I]
    _Float16* __restrict__ xp)         // [B][T][3H]
{
    const int blk = blockIdx.x;        // 256 b x 32 t-chunks = 8192
    const int b   = blk >> 5;
    const int t0  = (blk & 31) * 32;
    const int tid = threadIdx.x;
    const int l   = tid & 63;
    const int w   = tid >> 6;          // wave 0..3: gates [96w, 96w+96)
    const int ln  = l & 15;
    const int lg  = l >> 4;

    half8 bf[6][2];                    // B-frags: 6 subtiles x 2 kc
#pragma unroll
    for (int s = 0; s < 6; ++s) {
        const float* rp = W_ih + (size_t)(w * 96 + s * 16 + ln) * Ic;
#pragma unroll
        for (int kc = 0; kc < 2; ++kc) {
            const float* p = rp + kc * 32 + lg * 8;
            half8 f;
#pragma unroll
            for (int e = 0; e < 8; ++e) f[e] = (_Float16)p[e];
            bf[s][kc] = f;
        }
    }
    half8 af[2][2];                    // A-frags: 2 M-subtiles x 2 kc
#pragma unroll
    for (int ms = 0; ms < 2; ++ms) {
        int tr = t0 + ms * 16 + ln; if (tr > Tc - 1) tr = Tc - 1;
        const float* p0 = input + ((size_t)b * Tc + tr) * Ic + lg * 8;
#pragma unroll
        for (int kc = 0; kc < 2; ++kc) {
            const float* p = p0 + kc * 32;
            half8 f;
#pragma unroll
            for (int e = 0; e < 8; ++e) f[e] = (_Float16)p[e];
            af[ms][kc] = f;
        }
    }
#pragma unroll
    for (int ms = 0; ms < 2; ++ms) {
#pragma unroll
        for (int s = 0; s < 6; ++s) {
            f32x4 c = {0.f, 0.f, 0.f, 0.f};
            c = MFMA_F16(af[ms][0], bf[s][0], c);
            c = MFMA_F16(af[ms][1], bf[s][1], c);
            const int gc = w * 96 + s * 16 + ln;
#pragma unroll
            for (int i = 0; i < 4; ++i) {
                const int tr = t0 + ms * 16 + lg * 4 + i;
                if (tr < Tc) xp[((size_t)b * Tc + tr) * G3 + gc] = (_Float16)c[i];
            }
        }
    }
}

// ---------------- scan: h-recurrence only (12 MFMA/wave/step) ----------------
__global__ __launch_bounds__(512, 2) void gru_scan2(
    const float* __restrict__ W_hh,
    const float* __restrict__ b_ih,
    const float* __restrict__ b_hh,
    const _Float16* __restrict__ xp,   // [B][T][3H]
    float* __restrict__ out)
{
    const int blk = blockIdx.x;
    const int tid = threadIdx.x;
    const int l   = tid & 63;
    const int w   = tid >> 6;
    const int ln  = l & 15;
    const int lg  = l >> 4;
    const int j   = w * 16 + ln;
    const bool hi = (l >= 32);

    __shared__ __align__(16) _Float16 hbuf[2][16][136];  // rows 8-15 stay 0

    half8 bh[3][4];                     // W_hh B-frags (r12-identical)
#pragma unroll
    for (int g = 0; g < 3; ++g) {
        const float* rw = W_hh + (size_t)(g * Hc + j) * Hc;
#pragma unroll
        for (int kc = 0; kc < 4; ++kc) {
            const float* p = rw + kc * 32 + lg * 8;
            half8 f;
#pragma unroll
            for (int e = 0; e < 8; ++e) f[e] = (_Float16)p[e];
            bh[g][kc] = f;
        }
    }
    const float br0 = b_ih[j] + b_hh[j];
    const float bz0 = b_ih[Hc + j] + b_hh[Hc + j];
    const float bnx = b_ih[2 * Hc + j];
    const float bnh = b_hh[2 * Hc + j];

    for (int i = tid; i < 2 * 16 * 136; i += 512) (&hbuf[0][0][0])[i] = (_Float16)0.0f;
    __syncthreads();

    // lane's owned rows after redistribution (r12-identical)
    const int mA = (lg & 1) * 4 + (hi ? 2 : 0);
    const int mB = mA + 1;
    const int bA = blk * MBLK + mA;
    const int bB = blk * MBLK + mB;

    const unsigned short* pA = reinterpret_cast<const unsigned short*>(xp) + (size_t)bA * Tc * G3 + j;
    const unsigned short* pB = reinterpret_cast<const unsigned short*>(xp) + (size_t)bB * Tc * G3 + j;
    // prologue: xg(0) current values
    float xrA = cvt16(pA[0]), xzA = cvt16(pA[Hc]), xnA = cvt16(pA[2 * Hc]);
    float xrB = cvt16(pB[0]), xzB = cvt16(pB[Hc]), xnB = cvt16(pB[2 * Hc]);
    pA += G3; pB += G3;

    float holdA = 0.f, holdB = 0.f;
    float* sA  = out + (size_t)bA * Tc * Hc + j;
    float* sB  = out + (size_t)bB * Tc * Hc + j;
    float* hTp = out + (size_t)Bc * Tc * Hc;

#define GRU_STEP(T_, PAR_)                                                      \
    {                                                                           \
        __syncthreads();                                                        \
        /* prefetch xg(t+1) raw; converted at end of step (full-step slack) */  \
        const unsigned short qrA = pA[0], qzA = pA[Hc], qnA = pA[2 * Hc];       \
        const unsigned short qrB = pB[0], qzB = pB[Hc], qnB = pB[2 * Hc];       \
        if ((T_) + 2 < Tc) { pA += G3; pB += G3; }                              \
        const _Float16* hrp = &hbuf[1 - (PAR_)][ln][lg * 8];                    \
        half8 ha0 = *reinterpret_cast<const half8*>(hrp);                       \
        half8 ha1 = *reinterpret_cast<const half8*>(hrp + 32);                  \
        half8 ha2 = *reinterpret_cast<const half8*>(hrp + 64);                  \
        half8 ha3 = *reinterpret_cast<const half8*>(hrp + 96);                  \
        f32x4 cr = {br0, br0, br0, br0};                                        \
        f32x4 cz = {bz0, bz0, bz0, bz0};                                        \
        f32x4 ch = {bnh, bnh, bnh, bnh};                                        \
        cr = MFMA_F16(ha0, bh[0][0], cr); cz = MFMA_F16(ha0, bh[1][0], cz);     \
        ch = MFMA_F16(ha0, bh[2][0], ch);                                       \
        cr = MFMA_F16(ha1, bh[0][1], cr); cz = MFMA_F16(ha1, bh[1][1], cz);     \
        ch = MFMA_F16(ha1, bh[2][1], ch);                                       \
        cr = MFMA_F16(ha2, bh[0][2], cr); cz = MFMA_F16(ha2, bh[1][2], cz);     \
        ch = MFMA_F16(ha2, bh[2][2], ch);                                       \
        cr = MFMA_F16(ha3, bh[0][3], cr); cz = MFMA_F16(ha3, bh[1][3], cz);     \
        ch = MFMA_F16(ha3, bh[2][3], ch);                                       \
        /* redistribute elems 2,3 to the upper half-wave (6 shfl) */            \
        const float tR2 = __shfl_xor(cr[2], 32), tR3 = __shfl_xor(cr[3], 32);   \
        const float tZ2 = __shfl_xor(cz[2], 32), tZ3 = __shfl_xor(cz[3], 32);   \
        const float tH2 = __shfl_xor(ch[2], 32), tH3 = __shfl_xor(ch[3], 32);   \
        const float aR = (hi ? tR2 : cr[0]) + xrA;                              \
        const float bR = (hi ? tR3 : cr[1]) + xrB;                              \
        const float aZ = (hi ? tZ2 : cz[0]) + xzA;                              \
        const float bZ = (hi ? tZ3 : cz[1]) + xzB;                              \
        const float aH = hi ? tH2 : ch[0];                                      \
        const float bH = hi ? tH3 : ch[1];                                      \
        const float rgA = fast_sigmoid(aR), zgA = fast_sigmoid(aZ);             \
        const float nvA = fast_tanh(xnA + bnx + rgA * aH);                      \
        const float hA  = nvA + zgA * (holdA - nvA);                            \
        const float rgB = fast_sigmoid(bR), zgB = fast_sigmoid(bZ);             \
        const float nvB = fast_tanh(xnB + bnx + rgB * bH);                      \
        const float hB  = nvB + zgB * (holdB - nvB);                            \
        hbuf[PAR_][mA][j] = (_Float16)hA;                                       \
        hbuf[PAR_][mB][j] = (_Float16)hB;                                       \
        *sA = hA; sA += Hc;                                                     \
        *sB = hB; sB += Hc;                                                     \
        if ((T_) == Tc - 1) {                                                   \
            hTp[(size_t)bA * Hc + j] = hA;                                      \
            hTp[(size_t)bB * Hc + j] = hB;                                      \
        }                                                                       \
        holdA = hA; holdB = hB;                                                 \
        xrA = cvt16(qrA); xzA = cvt16(qzA); xnA = cvt16(qnA);                   \
        xrB = cvt16(qrB); xzB = cvt16(qzB); xnB = cvt16(qnB);                   \
    }

    for (int t = 0; t < Tc; t += 2) {
        GRU_STEP(t, 0);
        GRU_STEP(t + 1, 1);
    }
#undef GRU_STEP
}

// ---------------- fallback: r12 kernel verbatim (594us, ws-independent) ------
__global__ __launch_bounds__(512, 2) void gru_mfma_fb(
    const float* __restrict__ input, const float* __restrict__ W_ih,
    const float* __restrict__ W_hh, const float* __restrict__ b_ih,
    const float* __restrict__ b_hh, float* __restrict__ out)
{
    const int blk = blockIdx.x;
    const int tid = threadIdx.x;
    const int l   = tid & 63;
    const int w   = tid >> 6;
    const int ln  = l & 15;
    const int lg  = l >> 4;
    const int j   = w * 16 + ln;
    const bool hi = (l >= 32);

    __shared__ __align__(16) _Float16 hbuf[2][16][136];
    __shared__ __align__(16) _Float16 xbuf[2][16][72];

    half8 bh[3][4], bx[3][2];
#pragma unroll
    for (int g = 0; g < 3; ++g) {
        const float* rw = W_hh + (size_t)(g * Hc + j) * Hc;
#pragma unroll
        for (int kc = 0; kc < 4; ++kc) {
            const float* p = rw + kc * 32 + lg * 8;
            half8 f;
#pragma unroll
            for (int e = 0; e < 8; ++e) f[e] = (_Float16)p[e];
            bh[g][kc] = f;
        }
        const float* rx = W_ih + (size_t)(g * Hc + j) * Ic;
#pragma unroll
        for (int kc = 0; kc < 2; ++kc) {
            const float* p = rx + kc * 32 + lg * 8;
            half8 f;
#pragma unroll
            for (int e = 0; e < 8; ++e) f[e] = (_Float16)p[e];
            bx[g][kc] = f;
        }
    }
    const float br0 = b_ih[j] + b_hh[j];
    const float bz0 = b_ih[Hc + j] + b_hh[Hc + j];
    const float bnx = b_ih[2 * Hc + j];
    const float bnh = b_hh[2 * Hc + j];

    const int  sm  = tid >> 5;
    const int  sk  = (tid & 31) * 2;
    const bool stg = sm < MBLK;
    const float* inrow = input + (size_t)(blk * MBLK + (stg ? sm : 0)) * Tc * Ic + sk;

    for (int i = tid; i < 2 * 16 * 136; i += 512) (&hbuf[0][0][0])[i] = (_Float16)0.0f;
    for (int i = tid; i < 2 * 16 * 72;  i += 512) (&xbuf[0][0][0])[i] = (_Float16)0.0f;
    __syncthreads();

    float2 xpre0 = {0.f, 0.f}, xpre1 = {0.f, 0.f};
    if (stg) {
        float2 v0 = *reinterpret_cast<const float2*>(inrow);
        float2 v1 = *reinterpret_cast<const float2*>(inrow + Ic);
        union { _Float16 h[2]; unsigned u; } p0, p1;
        p0.h[0] = (_Float16)v0.x; p0.h[1] = (_Float16)v0.y;
        p1.h[0] = (_Float16)v1.x; p1.h[1] = (_Float16)v1.y;
        *reinterpret_cast<unsigned*>(&xbuf[0][sm][sk]) = p0.u;
        *reinterpret_cast<unsigned*>(&xbuf[1][sm][sk]) = p1.u;
        xpre0 = *reinterpret_cast<const float2*>(inrow + 2 * Ic);
        xpre1 = *reinterpret_cast<const float2*>(inrow + 3 * Ic);
    }
    __syncthreads();

    f32x4 cr  = {br0, br0, br0, br0};
    f32x4 cz  = {bz0, bz0, bz0, bz0};
    f32x4 cxn = {bnx, bnx, bnx, bnx};
    {
        const _Float16* xr = &xbuf[0][ln][lg * 8];
        half8 xa0 = *reinterpret_cast<const half8*>(xr);
        half8 xa1 = *reinterpret_cast<const half8*>(xr + 32);
        cr  = MFMA_F16(xa0, bx[0][0], cr);  cr  = MFMA_F16(xa1, bx[0][1], cr);
        cz  = MFMA_F16(xa0, bx[1][0], cz);  cz  = MFMA_F16(xa1, bx[1][1], cz);
        cxn = MFMA_F16(xa0, bx[2][0], cxn); cxn = MFMA_F16(xa1, bx[2][1], cxn);
    }
    float holdA = 0.f, holdB = 0.f;
    const int mA = (lg & 1) * 4 + (hi ? 2 : 0);
    const int mB = mA + 1;
    float* sA  = out + (size_t)(blk * MBLK + mA) * Tc * Hc + j;
    float* sB  = out + (size_t)(blk * MBLK + mB) * Tc * Hc + j;
    float* hTp = out + (size_t)Bc * Tc * Hc;

#define GRU_STEP_FB(T_, PAR_, XPRE_)                                            \
    {                                                                           \
        __syncthreads();                                                        \
        const _Float16* hrp = &hbuf[1 - (PAR_)][ln][lg * 8];                    \
        half8 ha0 = *reinterpret_cast<const half8*>(hrp);                       \
        half8 ha1 = *reinterpret_cast<const half8*>(hrp + 32);                  \
        half8 ha2 = *reinterpret_cast<const half8*>(hrp + 64);                  \
        half8 ha3 = *reinterpret_cast<const half8*>(hrp + 96);                  \
        f32x4 chn = {bnh, bnh, bnh, bnh};                                       \
        cr = MFMA_F16(ha0, bh[0][0], cr); cz = MFMA_F16(ha0, bh[1][0], cz);     \
        chn = MFMA_F16(ha0, bh[2][0], chn);                                     \
        cr = MFMA_F16(ha1, bh[0][1], cr); cz = MFMA_F16(ha1, bh[1][1], cz);     \
        chn = MFMA_F16(ha1, bh[2][1], chn);                                     \
        cr = MFMA_F16(ha2, bh[0][2], cr); cz = MFMA_F16(ha2, bh[1][2], cz);     \
        chn = MFMA_F16(ha2, bh[2][2], chn);                                     \
        cr = MFMA_F16(ha3, bh[0][3], cr); cz = MFMA_F16(ha3, bh[1][3], cz);     \
        chn = MFMA_F16(ha3, bh[2][3], chn);                                     \
        const _Float16* xrp = &xbuf[1 - (PAR_)][ln][lg * 8];                    \
        half8 xa0 = *reinterpret_cast<const half8*>(xrp);                       \
        half8 xa1 = *reinterpret_cast<const half8*>(xrp + 32);                  \
        f32x4 nr = {br0, br0, br0, br0};                                        \
        f32x4 nz = {bz0, bz0, bz0, bz0};                                        \
        f32x4 nx = {bnx, bnx, bnx, bnx};                                        \
        nr = MFMA_F16(xa0, bx[0][0], nr); nr = MFMA_F16(xa1, bx[0][1], nr);     \
        nz = MFMA_F16(xa0, bx[1][0], nz); nz = MFMA_F16(xa1, bx[1][1], nz);     \
        nx = MFMA_F16(xa0, bx[2][0], nx); nx = MFMA_F16(xa1, bx[2][1], nx);     \
        if (stg) {                                                              \
            union { _Float16 h[2]; unsigned u; } pk;                            \
            pk.h[0] = (_Float16)XPRE_.x; pk.h[1] = (_Float16)XPRE_.y;           \
            *reinterpret_cast<unsigned*>(&xbuf[PAR_][sm][sk]) = pk.u;           \
            const int trow = ((T_) + 4 < Tc) ? ((T_) + 4) : (Tc - 1);           \
            XPRE_ = *reinterpret_cast<const float2*>(inrow + (size_t)trow * Ic);\
        }                                                                       \
        const float tR2 = __shfl_xor(cr[2], 32),  tR3 = __shfl_xor(cr[3], 32);  \
        const float tZ2 = __shfl_xor(cz[2], 32),  tZ3 = __shfl_xor(cz[3], 32);  \
        const float tX2 = __shfl_xor(cxn[2], 32), tX3 = __shfl_xor(cxn[3], 32); \
        const float tH2 = __shfl_xor(chn[2], 32), tH3 = __shfl_xor(chn[3], 32); \
        const float aR = hi ? tR2 : cr[0],  bR = hi ? tR3 : cr[1];              \
        const float aZ = hi ? tZ2 : cz[0],  bZ = hi ? tZ3 : cz[1];              \
        const float aX = hi ? tX2 : cxn[0], bX = hi ? tX3 : cxn[1];             \
        const float aH = hi ? tH2 : chn[0], bH = hi ? tH3 : chn[1];             \
        const float rgA = fast_sigmoid(aR), zgA = fast_sigmoid(aZ);             \
        const float nvA = fast_tanh(aX + rgA * aH);                             \
        const float hA  = nvA + zgA * (holdA - nvA);                            \
        const float rgB = fast_sigmoid(bR), zgB = fast_sigmoid(bZ);             \
        const float nvB = fast_tanh(bX + rgB * bH);                             \
        const float hB  = nvB + zgB * (holdB - nvB);                            \
        hbuf[PAR_][mA][j] = (_Float16)hA;                                       \
        hbuf[PAR_][mB][j] = (_Float16)hB;                                       \
        *sA = hA; sA += Hc;                                                     \
        *sB = hB; sB += Hc;                                                     \
        if ((T_) == Tc - 1) {                                                   \
            hTp[(size_t)(blk * MBLK + mA) * Hc + j] = hA;                       \
            hTp[(size_t)(blk * MBLK + mB) * Hc + j] = hB;                       \
        }                                                                       \
        cr = nr; cz = nz; cxn = nx; holdA = hA; holdB = hB;                     \
    }

    for (int t = 0; t < Tc; t += 2) {
        GRU_STEP_FB(t, 0, xpre0);
        GRU_STEP_FB(t + 1, 1, xpre1);
    }
#undef GRU_STEP_FB
}

extern "C" void kernel_launch(void* const* d_in, const int* in_sizes, int n_in,
                              void* d_out, int out_size, void* d_ws, size_t ws_size,
                              hipStream_t stream) {
    const float* input = (const float*)d_in[0];
    const float* W_ih  = (const float*)d_in[1];
    const float* W_hh  = (const float*)d_in[2];
    const float* b_ih  = (const float*)d_in[3];
    const float* b_hh  = (const float*)d_in[4];
    float* out = (float*)d_out;
    (void)in_sizes; (void)n_in; (void)out_size;

    const size_t need = (size_t)Bc * Tc * G3 * sizeof(_Float16);   // 196.6 MB
    if (ws_size >= need) {
        _Float16* xp = (_Float16*)d_ws;
        xproj_kernel<<<Bc * 32, 256, 0, stream>>>(input, W_ih, xp);
        gru_scan2<<<NBLOCKS, 512, 0, stream>>>(W_hh, b_ih, b_hh, xp, out);
    } else {
        gru_mfma_fb<<<NBLOCKS, 512, 0, stream>>>(input, W_ih, W_hh, b_ih, b_hh, out);
    }
}

// Round 17
// 602.691 us; speedup vs baseline: 1.2160x; 1.2160x over previous
//
#include <hip/hip_runtime.h>

// GRU: B=256, T=1000, I=64, H=128 (3H=384).
// Round-17 = r12 (594us best) + ONE isolated change: states-store deferral.
// Evidence: r16 showed MFMA count is not binding (removing 6 MFMAs made the
// scan SLOWER); r15's regression is explained by r14 breaking the prefetch
// distance (load consumed same-step -> full HBM latency per step), so the
// store-deferral idea was never fairly tested. r12 issues 2 global stores
// ~30cyc before __syncthreads, whose vmcnt(0) drain then waits ~200-300cyc
// for store-ack EVERY step. Fix: keep hnew in pend regs, store at the TOP
// of the next step (a full ~1400cyc of drain slack). hT moved to epilogue.
// Everything else (prefetch distance, 4-deep chains, x-MFMA fusion,
// shuffle redistribution) byte-identical to r12.

#define Tc 1000
#define Ic 64
#define Hc 128
#define Bc 256
#define MBLK 8
#define NBLOCKS 32

typedef _Float16 half8 __attribute__((ext_vector_type(8)));
typedef float f32x4 __attribute__((ext_vector_type(4)));

#define MFMA_F16(A, B, C) __builtin_amdgcn_mfma_f32_16x16x32_f16((A), (B), (C), 0, 0, 0)

__device__ __forceinline__ float fast_sigmoid(float x) {
    return __builtin_amdgcn_rcpf(1.0f + __expf(-x));
}
__device__ __forceinline__ float fast_tanh(float x) {
    return 1.0f - 2.0f * __builtin_amdgcn_rcpf(__expf(2.0f * x) + 1.0f);
}

__global__ __launch_bounds__(512, 2) void gru_mfma_kernel(
    const float* __restrict__ input,   // [B][T][I]
    const float* __restrict__ W_ih,    // [3H][I]
    const float* __restrict__ W_hh,    // [3H][H]
    const float* __restrict__ b_ih,    // [3H]
    const float* __restrict__ b_hh,    // [3H]
    float* __restrict__ out)           // states [B][T][H] then hT [B][H]
{
    const int blk = blockIdx.x;
    const int tid = threadIdx.x;
    const int l   = tid & 63;
    const int w   = tid >> 6;    // wave 0..7
    const int ln  = l & 15;      // A-row m / B-col n offset
    const int lg  = l >> 4;      // k-group 0..3
    const int j   = w * 16 + ln; // this lane's gate column / h-unit
    const bool hi = (l >= 32);

    __shared__ __align__(16) _Float16 hbuf[2][16][136];  // h(t) f16; rows 8-15 stay 0
    __shared__ __align__(16) _Float16 xbuf[2][16][72];   // x rows f16; rows 8-15 stay 0

    // ---------- persistent B-fragments (identical to r11/r12, verified) ----------
    half8 bh[3][4], bx[3][2];
#pragma unroll
    for (int g = 0; g < 3; ++g) {
        const float* rw = W_hh + (size_t)(g * Hc + j) * Hc;
#pragma unroll
        for (int kc = 0; kc < 4; ++kc) {
            const float* p = rw + kc * 32 + lg * 8;
            half8 f;
#pragma unroll
            for (int e = 0; e < 8; ++e) f[e] = (_Float16)p[e];
            bh[g][kc] = f;
        }
        const float* rx = W_ih + (size_t)(g * Hc + j) * Ic;
#pragma unroll
        for (int kc = 0; kc < 2; ++kc) {
            const float* p = rx + kc * 32 + lg * 8;
            half8 f;
#pragma unroll
            for (int e = 0; e < 8; ++e) f[e] = (_Float16)p[e];
            bx[g][kc] = f;
        }
    }

    const float br0 = b_ih[j] + b_hh[j];
    const float bz0 = b_ih[Hc + j] + b_hh[Hc + j];
    const float bnx = b_ih[2 * Hc + j];
    const float bnh = b_hh[2 * Hc + j];

    // ---------- input staging geometry (8 real rows) ----------
    const int  sm  = tid >> 5;          // 0..15
    const int  sk  = (tid & 31) * 2;
    const bool stg = sm < MBLK;
    const float* inrow = input + (size_t)(blk * MBLK + (stg ? sm : 0)) * Tc * Ic + sk;

    // zero all of hbuf/xbuf (h(-1)=0; pad rows stay 0 forever)
    for (int i = tid; i < 2 * 16 * 136; i += 512) (&hbuf[0][0][0])[i] = (_Float16)0.0f;
    for (int i = tid; i < 2 * 16 * 72;  i += 512) (&xbuf[0][0][0])[i] = (_Float16)0.0f;
    __syncthreads();

    float2 xpre0 = {0.f, 0.f}, xpre1 = {0.f, 0.f};
    if (stg) {   // stage x rows 0,1; prefetch rows 2,3
        float2 v0 = *reinterpret_cast<const float2*>(inrow);
        float2 v1 = *reinterpret_cast<const float2*>(inrow + Ic);
        union { _Float16 h[2]; unsigned u; } p0, p1;
        p0.h[0] = (_Float16)v0.x; p0.h[1] = (_Float16)v0.y;
        p1.h[0] = (_Float16)v1.x; p1.h[1] = (_Float16)v1.y;
        *reinterpret_cast<unsigned*>(&xbuf[0][sm][sk]) = p0.u;
        *reinterpret_cast<unsigned*>(&xbuf[1][sm][sk]) = p1.u;
        xpre0 = *reinterpret_cast<const float2*>(inrow + 2 * Ic);
        xpre1 = *reinterpret_cast<const float2*>(inrow + 3 * Ic);
    }
    __syncthreads();

    // ---------- prologue: x-projection for t=0 ----------
    f32x4 cr  = {br0, br0, br0, br0};
    f32x4 cz  = {bz0, bz0, bz0, bz0};
    f32x4 cxn = {bnx, bnx, bnx, bnx};
    {
        const _Float16* xr = &xbuf[0][ln][lg * 8];
        half8 xa0 = *reinterpret_cast<const half8*>(xr);
        half8 xa1 = *reinterpret_cast<const half8*>(xr + 32);
        cr  = MFMA_F16(xa0, bx[0][0], cr);  cr  = MFMA_F16(xa1, bx[0][1], cr);
        cz  = MFMA_F16(xa0, bx[1][0], cz);  cz  = MFMA_F16(xa1, bx[1][1], cz);
        cxn = MFMA_F16(xa0, bx[2][0], cxn); cxn = MFMA_F16(xa1, bx[2][1], cxn);
    }
    float holdA = 0.f, holdB = 0.f;
    float pendA = 0.f, pendB = 0.f;   // h(t-1) awaiting deferred global store

    // this lane's two owned batch rows after redistribution
    const int mA = (lg & 1) * 4 + (hi ? 2 : 0);
    const int mB = mA + 1;
    float* sA  = out + (size_t)(blk * MBLK + mA) * Tc * Hc + j;   // states run-ptr
    float* sB  = out + (size_t)(blk * MBLK + mB) * Tc * Hc + j;
    float* hTp = out + (size_t)Bc * Tc * Hc;

// ST_: 1 = store previous step's pend (all steps except the very first)
#define GRU_STEP(T_, PAR_, XPRE_, ST_)                                          \
    {                                                                           \
        __syncthreads();                                                        \
        /* deferred store: full step of drain slack before next barrier */      \
        if (ST_) {                                                              \
            *sA = pendA; sA += Hc;                                              \
            *sB = pendB; sB += Hc;                                              \
        }                                                                       \
        const _Float16* hrp = &hbuf[1 - (PAR_)][ln][lg * 8];                    \
        half8 ha0 = *reinterpret_cast<const half8*>(hrp);                       \
        half8 ha1 = *reinterpret_cast<const half8*>(hrp + 32);                  \
        half8 ha2 = *reinterpret_cast<const half8*>(hrp + 64);                  \
        half8 ha3 = *reinterpret_cast<const half8*>(hrp + 96);                  \
        f32x4 chn = {bnh, bnh, bnh, bnh};                                       \
        cr = MFMA_F16(ha0, bh[0][0], cr); cz = MFMA_F16(ha0, bh[1][0], cz);     \
        chn = MFMA_F16(ha0, bh[2][0], chn);                                     \
        cr = MFMA_F16(ha1, bh[0][1], cr); cz = MFMA_F16(ha1, bh[1][1], cz);     \
        chn = MFMA_F16(ha1, bh[2][1], chn);                                     \
        cr = MFMA_F16(ha2, bh[0][2], cr); cz = MFMA_F16(ha2, bh[1][2], cz);     \
        chn = MFMA_F16(ha2, bh[2][2], chn);                                     \
        cr = MFMA_F16(ha3, bh[0][3], cr); cz = MFMA_F16(ha3, bh[1][3], cz);     \
        chn = MFMA_F16(ha3, bh[2][3], chn);                                     \
        const _Float16* xrp = &xbuf[1 - (PAR_)][ln][lg * 8];                    \
        half8 xa0 = *reinterpret_cast<const half8*>(xrp);                       \
        half8 xa1 = *reinterpret_cast<const half8*>(xrp + 32);                  \
        f32x4 nr = {br0, br0, br0, br0};                                        \
        f32x4 nz = {bz0, bz0, bz0, bz0};                                        \
        f32x4 nx = {bnx, bnx, bnx, bnx};                                        \
        nr = MFMA_F16(xa0, bx[0][0], nr); nr = MFMA_F16(xa1, bx[0][1], nr);     \
        nz = MFMA_F16(xa0, bx[1][0], nz); nz = MFMA_F16(xa1, bx[1][1], nz);     \
        nx = MFMA_F16(xa0, bx[2][0], nx); nx = MFMA_F16(xa1, bx[2][1], nx);     \
        if (stg) {                                                              \
            union { _Float16 h[2]; unsigned u; } pk;                            \
            pk.h[0] = (_Float16)XPRE_.x; pk.h[1] = (_Float16)XPRE_.y;           \
            *reinterpret_cast<unsigned*>(&xbuf[PAR_][sm][sk]) = pk.u;           \
            const int trow = ((T_) + 4 < Tc) ? ((T_) + 4) : (Tc - 1);           \
            XPRE_ = *reinterpret_cast<const float2*>(inrow + (size_t)trow * Ic);\
        }                                                                       \
        /* redistribute elems 2,3 to the upper half-wave */                     \
        const float tR2 = __shfl_xor(cr[2], 32),  tR3 = __shfl_xor(cr[3], 32);  \
        const float tZ2 = __shfl_xor(cz[2], 32),  tZ3 = __shfl_xor(cz[3], 32);  \
        const float tX2 = __shfl_xor(cxn[2], 32), tX3 = __shfl_xor(cxn[3], 32); \
        const float tH2 = __shfl_xor(chn[2], 32), tH3 = __shfl_xor(chn[3], 32); \
        const float aR = hi ? tR2 : cr[0],  bR = hi ? tR3 : cr[1];              \
        const float aZ = hi ? tZ2 : cz[0],  bZ = hi ? tZ3 : cz[1];              \
        const float aX = hi ? tX2 : cxn[0], bX = hi ? tX3 : cxn[1];             \
        const float aH = hi ? tH2 : chn[0], bH = hi ? tH3 : chn[1];             \
        const float rgA = fast_sigmoid(aR), zgA = fast_sigmoid(aZ);             \
        const float nvA = fast_tanh(aX + rgA * aH);                             \
        const float hA  = nvA + zgA * (holdA - nvA);                            \
        const float rgB = fast_sigmoid(bR), zgB = fast_sigmoid(bZ);             \
        const float nvB = fast_tanh(bX + rgB * bH);                             \
        const float hB  = nvB + zgB * (holdB - nvB);                            \
        hbuf[PAR_][mA][j] = (_Float16)hA;                                       \
        hbuf[PAR_][mB][j] = (_Float16)hB;                                       \
        pendA = hA; pendB = hB;                                                 \
        cr = nr; cz = nz; cxn = nx; holdA = hA; holdB = hB;                     \
    }

    // peeled first pair (no pending store yet at t=0)
    GRU_STEP(0, 0, xpre0, 0);
    GRU_STEP(1, 1, xpre1, 1);
    for (int t = 2; t < Tc; t += 2) {
        GRU_STEP(t, 0, xpre0, 1);
        GRU_STEP(t + 1, 1, xpre1, 1);
    }
#undef GRU_STEP

    // epilogue: final states row (t = Tc-1) + hT
    *sA = pendA;
    *sB = pendB;
    hTp[(size_t)(blk * MBLK + mA) * Hc + j] = pendA;
    hTp[(size_t)(blk * MBLK + mB) * Hc + j] = pendB;
}

extern "C" void kernel_launch(void* const* d_in, const int* in_sizes, int n_in,
                              void* d_out, int out_size, void* d_ws, size_t ws_size,
                              hipStream_t stream) {
    const float* input = (const float*)d_in[0];
    const float* W_ih  = (const float*)d_in[1];
    const float* W_hh  = (const float*)d_in[2];
    const float* b_ih  = (const float*)d_in[3];
    const float* b_hh  = (const float*)d_in[4];
    float* out = (float*)d_out;
    (void)in_sizes; (void)n_in; (void)d_ws; (void)ws_size; (void)out_size;

    gru_mfma_kernel<<<NBLOCKS, 512, 0, stream>>>(input, W_ih, W_hh, b_ih, b_hh, out);
}

// Round 18
// 592.585 us; speedup vs baseline: 1.2367x; 1.0171x over previous
//
#include <hip/hip_runtime.h>

// GRU: B=256, T=1000, I=64, H=128 (3H=384).
// Round-18 = r12 (594us best) + ONE isolated change: raw s_barrier with
// lgkmcnt-only wait instead of __syncthreads.
// Evidence: __syncthreads lowers to s_waitcnt vmcnt(0) lgkmcnt(0) + s_barrier
// (guide §5, m97 asm) -> the mid-step XPRE_ prefetch load must COMPLETE at
// every barrier, erasing its 4-step slack (L3 latency ~400-500cyc, partially
// exposed each step). r17 (store-deferral) was neutral -> stores aren't the
// cost; the load drain is the remaining suspect. LDS double-buffer
// correctness needs only lgkmcnt(0) before s_barrier; vmcnt waits are
// inserted by the compiler at actual consumption points (counted, covered).
// Everything else byte-identical to r12.

#define Tc 1000
#define Ic 64
#define Hc 128
#define Bc 256
#define MBLK 8
#define NBLOCKS 32

typedef _Float16 half8 __attribute__((ext_vector_type(8)));
typedef float f32x4 __attribute__((ext_vector_type(4)));

#define MFMA_F16(A, B, C) __builtin_amdgcn_mfma_f32_16x16x32_f16((A), (B), (C), 0, 0, 0)

// barrier with LDS-ordering only: no vmcnt(0) drain (T4 counted-vmcnt pattern)
#define BAR_LDS() asm volatile("s_waitcnt lgkmcnt(0)\n\ts_barrier" ::: "memory")

__device__ __forceinline__ float fast_sigmoid(float x) {
    return __builtin_amdgcn_rcpf(1.0f + __expf(-x));
}
__device__ __forceinline__ float fast_tanh(float x) {
    return 1.0f - 2.0f * __builtin_amdgcn_rcpf(__expf(2.0f * x) + 1.0f);
}

__global__ __launch_bounds__(512, 2) void gru_mfma_kernel(
    const float* __restrict__ input,   // [B][T][I]
    const float* __restrict__ W_ih,    // [3H][I]
    const float* __restrict__ W_hh,    // [3H][H]
    const float* __restrict__ b_ih,    // [3H]
    const float* __restrict__ b_hh,    // [3H]
    float* __restrict__ out)           // states [B][T][H] then hT [B][H]
{
    const int blk = blockIdx.x;
    const int tid = threadIdx.x;
    const int l   = tid & 63;
    const int w   = tid >> 6;    // wave 0..7
    const int ln  = l & 15;      // A-row m / B-col n offset
    const int lg  = l >> 4;      // k-group 0..3
    const int j   = w * 16 + ln; // this lane's gate column / h-unit
    const bool hi = (l >= 32);

    __shared__ __align__(16) _Float16 hbuf[2][16][136];  // h(t) f16; rows 8-15 stay 0
    __shared__ __align__(16) _Float16 xbuf[2][16][72];   // x rows f16; rows 8-15 stay 0

    // ---------- persistent B-fragments (identical to r11/r12, verified) ----------
    half8 bh[3][4], bx[3][2];
#pragma unroll
    for (int g = 0; g < 3; ++g) {
        const float* rw = W_hh + (size_t)(g * Hc + j) * Hc;
#pragma unroll
        for (int kc = 0; kc < 4; ++kc) {
            const float* p = rw + kc * 32 + lg * 8;
            half8 f;
#pragma unroll
            for (int e = 0; e < 8; ++e) f[e] = (_Float16)p[e];
            bh[g][kc] = f;
        }
        const float* rx = W_ih + (size_t)(g * Hc + j) * Ic;
#pragma unroll
        for (int kc = 0; kc < 2; ++kc) {
            const float* p = rx + kc * 32 + lg * 8;
            half8 f;
#pragma unroll
            for (int e = 0; e < 8; ++e) f[e] = (_Float16)p[e];
            bx[g][kc] = f;
        }
    }

    const float br0 = b_ih[j] + b_hh[j];
    const float bz0 = b_ih[Hc + j] + b_hh[Hc + j];
    const float bnx = b_ih[2 * Hc + j];
    const float bnh = b_hh[2 * Hc + j];

    // ---------- input staging geometry (8 real rows) ----------
    const int  sm  = tid >> 5;          // 0..15
    const int  sk  = (tid & 31) * 2;
    const bool stg = sm < MBLK;
    const float* inrow = input + (size_t)(blk * MBLK + (stg ? sm : 0)) * Tc * Ic + sk;

    // zero all of hbuf/xbuf (h(-1)=0; pad rows stay 0 forever)
    for (int i = tid; i < 2 * 16 * 136; i += 512) (&hbuf[0][0][0])[i] = (_Float16)0.0f;
    for (int i = tid; i < 2 * 16 * 72;  i += 512) (&xbuf[0][0][0])[i] = (_Float16)0.0f;
    __syncthreads();

    float2 xpre0 = {0.f, 0.f}, xpre1 = {0.f, 0.f};
    if (stg) {   // stage x rows 0,1; prefetch rows 2,3
        float2 v0 = *reinterpret_cast<const float2*>(inrow);
        float2 v1 = *reinterpret_cast<const float2*>(inrow + Ic);
        union { _Float16 h[2]; unsigned u; } p0, p1;
        p0.h[0] = (_Float16)v0.x; p0.h[1] = (_Float16)v0.y;
        p1.h[0] = (_Float16)v1.x; p1.h[1] = (_Float16)v1.y;
        *reinterpret_cast<unsigned*>(&xbuf[0][sm][sk]) = p0.u;
        *reinterpret_cast<unsigned*>(&xbuf[1][sm][sk]) = p1.u;
        xpre0 = *reinterpret_cast<const float2*>(inrow + 2 * Ic);
        xpre1 = *reinterpret_cast<const float2*>(inrow + 3 * Ic);
    }
    __syncthreads();

    // ---------- prologue: x-projection for t=0 ----------
    f32x4 cr  = {br0, br0, br0, br0};
    f32x4 cz  = {bz0, bz0, bz0, bz0};
    f32x4 cxn = {bnx, bnx, bnx, bnx};
    {
        const _Float16* xr = &xbuf[0][ln][lg * 8];
        half8 xa0 = *reinterpret_cast<const half8*>(xr);
        half8 xa1 = *reinterpret_cast<const half8*>(xr + 32);
        cr  = MFMA_F16(xa0, bx[0][0], cr);  cr  = MFMA_F16(xa1, bx[0][1], cr);
        cz  = MFMA_F16(xa0, bx[1][0], cz);  cz  = MFMA_F16(xa1, bx[1][1], cz);
        cxn = MFMA_F16(xa0, bx[2][0], cxn); cxn = MFMA_F16(xa1, bx[2][1], cxn);
    }
    float holdA = 0.f, holdB = 0.f;

    // this lane's two owned batch rows after redistribution
    const int mA = (lg & 1) * 4 + (hi ? 2 : 0);
    const int mB = mA + 1;
    float* sA  = out + (size_t)(blk * MBLK + mA) * Tc * Hc + j;   // states run-ptr
    float* sB  = out + (size_t)(blk * MBLK + mB) * Tc * Hc + j;
    float* hTp = out + (size_t)Bc * Tc * Hc;

#define GRU_STEP(T_, PAR_, XPRE_)                                               \
    {                                                                           \
        BAR_LDS();                                                              \
        const _Float16* hrp = &hbuf[1 - (PAR_)][ln][lg * 8];                    \
        half8 ha0 = *reinterpret_cast<const half8*>(hrp);                       \
        half8 ha1 = *reinterpret_cast<const half8*>(hrp + 32);                  \
        half8 ha2 = *reinterpret_cast<const half8*>(hrp + 64);                  \
        half8 ha3 = *reinterpret_cast<const half8*>(hrp + 96);                  \
        f32x4 chn = {bnh, bnh, bnh, bnh};                                       \
        cr = MFMA_F16(ha0, bh[0][0], cr); cz = MFMA_F16(ha0, bh[1][0], cz);     \
        chn = MFMA_F16(ha0, bh[2][0], chn);                                     \
        cr = MFMA_F16(ha1, bh[0][1], cr); cz = MFMA_F16(ha1, bh[1][1], cz);     \
        chn = MFMA_F16(ha1, bh[2][1], chn);                                     \
        cr = MFMA_F16(ha2, bh[0][2], cr); cz = MFMA_F16(ha2, bh[1][2], cz);     \
        chn = MFMA_F16(ha2, bh[2][2], chn);                                     \
        cr = MFMA_F16(ha3, bh[0][3], cr); cz = MFMA_F16(ha3, bh[1][3], cz);     \
        chn = MFMA_F16(ha3, bh[2][3], chn);                                     \
        const _Float16* xrp = &xbuf[1 - (PAR_)][ln][lg * 8];                    \
        half8 xa0 = *reinterpret_cast<const half8*>(xrp);                       \
        half8 xa1 = *reinterpret_cast<const half8*>(xrp + 32);                  \
        f32x4 nr = {br0, br0, br0, br0};                                        \
        f32x4 nz = {bz0, bz0, bz0, bz0};                                        \
        f32x4 nx = {bnx, bnx, bnx, bnx};                                        \
        nr = MFMA_F16(xa0, bx[0][0], nr); nr = MFMA_F16(xa1, bx[0][1], nr);     \
        nz = MFMA_F16(xa0, bx[1][0], nz); nz = MFMA_F16(xa1, bx[1][1], nz);     \
        nx = MFMA_F16(xa0, bx[2][0], nx); nx = MFMA_F16(xa1, bx[2][1], nx);     \
        if (stg) {                                                              \
            union { _Float16 h[2]; unsigned u; } pk;                            \
            pk.h[0] = (_Float16)XPRE_.x; pk.h[1] = (_Float16)XPRE_.y;           \
            *reinterpret_cast<unsigned*>(&xbuf[PAR_][sm][sk]) = pk.u;           \
            const int trow = ((T_) + 4 < Tc) ? ((T_) + 4) : (Tc - 1);           \
            XPRE_ = *reinterpret_cast<const float2*>(inrow + (size_t)trow * Ic);\
        }                                                                       \
        /* redistribute elems 2,3 to the upper half-wave */                     \
        const float tR2 = __shfl_xor(cr[2], 32),  tR3 = __shfl_xor(cr[3], 32);  \
        const float tZ2 = __shfl_xor(cz[2], 32),  tZ3 = __shfl_xor(cz[3], 32);  \
        const float tX2 = __shfl_xor(cxn[2], 32), tX3 = __shfl_xor(cxn[3], 32); \
        const float tH2 = __shfl_xor(chn[2], 32), tH3 = __shfl_xor(chn[3], 32); \
        const float aR = hi ? tR2 : cr[0],  bR = hi ? tR3 : cr[1];              \
        const float aZ = hi ? tZ2 : cz[0],  bZ = hi ? tZ3 : cz[1];              \
        const float aX = hi ? tX2 : cxn[0], bX = hi ? tX3 : cxn[1];             \
        const float aH = hi ? tH2 : chn[0], bH = hi ? tH3 : chn[1];             \
        const float rgA = fast_sigmoid(aR), zgA = fast_sigmoid(aZ);             \
        const float nvA = fast_tanh(aX + rgA * aH);                             \
        const float hA  = nvA + zgA * (holdA - nvA);                            \
        const float rgB = fast_sigmoid(bR), zgB = fast_sigmoid(bZ);             \
        const float nvB = fast_tanh(bX + rgB * bH);                             \
        const float hB  = nvB + zgB * (holdB - nvB);                            \
        hbuf[PAR_][mA][j] = (_Float16)hA;                                       \
        hbuf[PAR_][mB][j] = (_Float16)hB;                                       \
        *sA = hA; sA += Hc;                                                     \
        *sB = hB; sB += Hc;                                                     \
        if ((T_) == Tc - 1) {                                                   \
            hTp[(size_t)(blk * MBLK + mA) * Hc + j] = hA;                       \
            hTp[(size_t)(blk * MBLK + mB) * Hc + j] = hB;                       \
        }                                                                       \
        cr = nr; cz = nz; cxn = nx; holdA = hA; holdB = hB;                     \
    }

    for (int t = 0; t < Tc; t += 2) {
        GRU_STEP(t, 0, xpre0);
        GRU_STEP(t + 1, 1, xpre1);
    }
#undef GRU_STEP
}

extern "C" void kernel_launch(void* const* d_in, const int* in_sizes, int n_in,
                              void* d_out, int out_size, void* d_ws, size_t ws_size,
                              hipStream_t stream) {
    const float* input = (const float*)d_in[0];
    const float* W_ih  = (const float*)d_in[1];
    const float* W_hh  = (const float*)d_in[2];
    const float* b_ih  = (const float*)d_in[3];
    const float* b_hh  = (const float*)d_in[4];
    float* out = (float*)d_out;
    (void)in_sizes; (void)n_in; (void)d_ws; (void)ws_size; (void)out_size;

    gru_mfma_kernel<<<NBLOCKS, 512, 0, stream>>>(input, W_ih, W_hh, b_ih, b_hh, out);
}